// Round 7
// baseline (685.839 us; speedup 1.0000x reference)
//
#include <hip/hip_runtime.h>

#define NN   100000
#define BSH  7                      // 128 nodes per bucket
#define NBKT ((NN + 127) / 128)     // 782
#define CAP  2560                   // slots per bucket (mean 2048, +11 sigma safe)
#define EPT  32                     // edges per thread in partition

// ---------------------------------------------------------------------------
// gcur[b] = b*CAP  (bucket cursor init; ws is poisoned before every launch)
// ---------------------------------------------------------------------------
__global__ void initcur_kernel(int* __restrict__ gcur) {
    int b = blockIdx.x * 256 + threadIdx.x;
    if (b < NBKT) gcur[b] = b * CAP;
}

// ---------------------------------------------------------------------------
// Partition edges by dst bucket. Per block: LDS histogram -> one global
// atomic per touched bucket (reserve run) -> write packed (src<<7|dst&127).
// ~150K global atomics instead of fill's 1.6M; run-contiguous writes.
// ---------------------------------------------------------------------------
__global__ void partition_kernel(const int* __restrict__ src,
                                 const int* __restrict__ dst,
                                 int* __restrict__ gcur,
                                 int* __restrict__ bkted, int E) {
    __shared__ int hist[NBKT];
    __shared__ int gbase[NBKT];
    int t = threadIdx.x;
    for (int b = t; b < NBKT; b += 256) hist[b] = 0;
    __syncthreads();

    int base = blockIdx.x * (256 * EPT);
    int rank[EPT];
#pragma unroll
    for (int i = 0; i < EPT; ++i) {
        int e = base + t + i * 256;
        rank[i] = -1;
        if (e < E) rank[i] = atomicAdd(&hist[dst[e] >> BSH], 1);
    }
    __syncthreads();
    for (int b = t; b < NBKT; b += 256) {
        int c = hist[b];
        gbase[b] = c ? atomicAdd(&gcur[b], c) : 0;
    }
    __syncthreads();
#pragma unroll
    for (int i = 0; i < EPT; ++i) {
        int e = base + t + i * 256;
        if (e < E) {
            int d = dst[e];
            int bk = d >> BSH;
            int pos = gbase[bk] + rank[i];
            if (pos < (bk + 1) * CAP)                        // overflow guard
                bkted[pos] = (src[e] << BSH) | (d & 127);
        }
    }
}

// ---------------------------------------------------------------------------
// Pre-transform layer 1:  y1 = x @ W1_l ,  z1 = x @ W1_r + b1
// (mean-aggregation is linear: mean(x)@W = mean(x@W))
// ---------------------------------------------------------------------------
__global__ void transform1_kernel(const float* __restrict__ x,
                                  const float* __restrict__ Wl,
                                  const float* __restrict__ Wr,
                                  const float* __restrict__ b,
                                  float* __restrict__ y,
                                  float* __restrict__ z) {
    __shared__ float sWl[32 * 32];
    __shared__ float sWr[32 * 32];
    __shared__ float sb[32];
    int t = threadIdx.x;
    for (int i = t; i < 1024; i += 256) { sWl[i] = Wl[i]; sWr[i] = Wr[i]; }
    if (t < 32) sb[t] = b[t];
    __syncthreads();

    int node = blockIdx.x * 8 + (t >> 5);
    if (node >= NN) return;
    int o = t & 31;
    const float* xr = x + (size_t)node * 32;
    float accl = 0.0f, accr = sb[o];
#pragma unroll
    for (int k = 0; k < 32; ++k) {
        float xv = xr[k];
        accl += xv * sWl[k * 32 + o];
        accr += xv * sWr[k * 32 + o];
    }
    y[(size_t)node * 32 + o] = accl;
    z[(size_t)node * 32 + o] = accr;
}

// ---------------------------------------------------------------------------
// Pre-transform layer 2:  y2 = h @ W2_l ,  z2 = h @ W2_r + b2
// ---------------------------------------------------------------------------
__global__ void transform2_kernel(const float* __restrict__ h,
                                  const float* __restrict__ Wl,
                                  const float* __restrict__ Wr,
                                  const float* __restrict__ b,
                                  float* __restrict__ y,
                                  float* __restrict__ z) {
    __shared__ float sWl[32 * 16];
    __shared__ float sWr[32 * 16];
    __shared__ float sb[16];
    int t = threadIdx.x;
    for (int i = t; i < 512; i += 256) { sWl[i] = Wl[i]; sWr[i] = Wr[i]; }
    if (t < 16) sb[t] = b[t];
    __syncthreads();

    int node = blockIdx.x * 16 + (t >> 4);
    if (node >= NN) return;
    int o = t & 15;
    const float* hr = h + (size_t)node * 32;
    float accl = 0.0f, accr = sb[o];
#pragma unroll
    for (int k = 0; k < 32; ++k) {
        float hv = hr[k];
        accl += hv * sWl[k * 16 + o];
        accr += hv * sWr[k * 16 + o];
    }
    y[(size_t)node * 16 + o] = accl;
    z[(size_t)node * 16 + o] = accr;
}

// ---------------------------------------------------------------------------
// Bucketed aggregation layer 1: one block per bucket (128 nodes).
// LDS acc[128][33]: cols 0..31 = running sum of y[src], col 32 = degree.
// Stride 33 breaks the 128B full-bank-wrap conflict (bank = (dl+4c+k)%32).
// Epilogue fused: h[g] = relu(acc/deg + z[g])   (h aliases z, in place).
// 8 lanes per edge, float4 each.
// ---------------------------------------------------------------------------
__global__ void aggbkt1_kernel(const float* __restrict__ y,
                               const int* __restrict__ gcur,
                               const int* __restrict__ bkted,
                               float* __restrict__ hz) {
    __shared__ float acc[128 * 33];
    int t = threadIdx.x;
    for (int i = t; i < 128 * 33; i += 256) acc[i] = 0.0f;
    __syncthreads();

    int b = blockIdx.x;
    int cnt = gcur[b] - b * CAP;
    if (cnt > CAP) cnt = CAP;
    int c = t & 7;
    const int* be = bkted + b * CAP;
    for (int j = t >> 3; j < cnt; j += 32) {
        int p = be[j];
        int s = p >> BSH;
        int dl = p & 127;
        const float4 v = *reinterpret_cast<const float4*>(y + (size_t)s * 32 + c * 4);
        float* a = &acc[dl * 33 + c * 4];
        atomicAdd(a + 0, v.x);
        atomicAdd(a + 1, v.y);
        atomicAdd(a + 2, v.z);
        atomicAdd(a + 3, v.w);
        if (c == 0) atomicAdd(&acc[dl * 33 + 32], 1.0f);
    }
    __syncthreads();

    for (int i = t; i < 1024; i += 256) {          // 128 nodes x 8 quads
        int dl = i >> 3, cc = i & 7;
        int g = (b << BSH) + dl;
        if (g >= NN) continue;
        float rd = 1.0f / fmaxf(acc[dl * 33 + 32], 1.0f);
        const float* ap = &acc[dl * 33 + cc * 4];
        float4* hp = reinterpret_cast<float4*>(hz + (size_t)g * 32 + cc * 4);
        const float4 zv = *hp;
        float4 r;
        r.x = fmaxf(ap[0] * rd + zv.x, 0.0f);
        r.y = fmaxf(ap[1] * rd + zv.y, 0.0f);
        r.z = fmaxf(ap[2] * rd + zv.z, 0.0f);
        r.w = fmaxf(ap[3] * rd + zv.w, 0.0f);
        *hp = r;
    }
}

// ---------------------------------------------------------------------------
// Bucketed aggregation layer 2 (16-wide): acc[128][17], col 16 = degree.
// 4 lanes per edge. out[g] = acc/deg + z2[g]  (no relu).
// ---------------------------------------------------------------------------
__global__ void aggbkt2_kernel(const float* __restrict__ y,
                               const float* __restrict__ z,
                               const int* __restrict__ gcur,
                               const int* __restrict__ bkted,
                               float* __restrict__ out) {
    __shared__ float acc[128 * 17];
    int t = threadIdx.x;
    for (int i = t; i < 128 * 17; i += 256) acc[i] = 0.0f;
    __syncthreads();

    int b = blockIdx.x;
    int cnt = gcur[b] - b * CAP;
    if (cnt > CAP) cnt = CAP;
    int c = t & 3;
    const int* be = bkted + b * CAP;
    for (int j = t >> 2; j < cnt; j += 64) {
        int p = be[j];
        int s = p >> BSH;
        int dl = p & 127;
        const float4 v = *reinterpret_cast<const float4*>(y + (size_t)s * 16 + c * 4);
        float* a = &acc[dl * 17 + c * 4];
        atomicAdd(a + 0, v.x);
        atomicAdd(a + 1, v.y);
        atomicAdd(a + 2, v.z);
        atomicAdd(a + 3, v.w);
        if (c == 0) atomicAdd(&acc[dl * 17 + 16], 1.0f);
    }
    __syncthreads();

    for (int i = t; i < 512; i += 256) {           // 128 nodes x 4 quads
        int dl = i >> 2, cc = i & 3;
        int g = (b << BSH) + dl;
        if (g >= NN) continue;
        float rd = 1.0f / fmaxf(acc[dl * 17 + 16], 1.0f);
        const float* ap = &acc[dl * 17 + cc * 4];
        const float4 zv = *reinterpret_cast<const float4*>(z + (size_t)g * 16 + cc * 4);
        float4 r;
        r.x = ap[0] * rd + zv.x;
        r.y = ap[1] * rd + zv.y;
        r.z = ap[2] * rd + zv.z;
        r.w = ap[3] * rd + zv.w;
        *reinterpret_cast<float4*>(out + (size_t)g * 16 + cc * 4) = r;
    }
}

extern "C" void kernel_launch(void* const* d_in, const int* in_sizes, int n_in,
                              void* d_out, int out_size, void* d_ws, size_t ws_size,
                              hipStream_t stream) {
    const float* x   = (const float*)d_in[0];
    const int*   ei  = (const int*)d_in[1];
    const float* W1l = (const float*)d_in[2];
    const float* W1r = (const float*)d_in[3];
    const float* b1  = (const float*)d_in[4];
    const float* W2l = (const float*)d_in[5];
    const float* W2r = (const float*)d_in[6];
    const float* b2  = (const float*)d_in[7];
    float* out = (float*)d_out;

    const int E = in_sizes[1] / 2;
    const int* src = ei;
    const int* dst = ei + E;

    // Workspace: gcur[1024] | bkted[NBKT*CAP] | A[NN*32] | B[NN*32]
    //   A: y1, then reused as y2[NN*16] | z2[NN*16]
    //   B: z1, overwritten in place by h
    char* ws = (char*)d_ws;
    int*   gcur  = (int*)ws;                      ws += 1024 * 4;
    int*   bkted = (int*)ws;                      ws += (size_t)NBKT * CAP * 4;
    float* A     = (float*)ws;                    ws += (size_t)NN * 32 * 4;
    float* B     = (float*)ws;

    float* y1  = A;
    float* z1h = B;                 // z1, becomes h in place
    float* y2  = A;                 // first NN*16 of A
    float* z2  = A + (size_t)NN * 16;

    // Bucket partition (once; reused by both layers)
    initcur_kernel<<<(NBKT + 255) / 256, 256, 0, stream>>>(gcur);
    partition_kernel<<<(E + 256 * EPT - 1) / (256 * EPT), 256, 0, stream>>>(
        src, dst, gcur, bkted, E);

    // Layer 1
    transform1_kernel<<<(NN + 7) / 8, 256, 0, stream>>>(x, W1l, W1r, b1, y1, z1h);
    aggbkt1_kernel<<<NBKT, 256, 0, stream>>>(y1, gcur, bkted, z1h);

    // Layer 2
    transform2_kernel<<<(NN + 15) / 16, 256, 0, stream>>>(z1h, W2l, W2r, b2, y2, z2);
    aggbkt2_kernel<<<NBKT, 256, 0, stream>>>(y2, z2, gcur, bkted, out);
}

// Round 9
// 227.976 us; speedup vs baseline: 3.0084x; 3.0084x over previous
//
#include <hip/hip_runtime.h>

#define NN   100000
#define BSH  7                      // 128 nodes per bucket
#define NBKT ((NN + 127) / 128)     // 782
#define CAP  2560                   // slots per bucket (mean 2048, +11 sigma)
#define EPT  32                     // edges per thread in partition

// ---------------------------------------------------------------------------
// gcur[b] = b*CAP  (bucket cursor init; ws is poisoned before every launch)
// ---------------------------------------------------------------------------
__global__ void initcur_kernel(int* __restrict__ gcur) {
    int b = blockIdx.x * 256 + threadIdx.x;
    if (b < NBKT) gcur[b] = b * CAP;
}

// ---------------------------------------------------------------------------
// Partition edges by dst bucket (validated R7). Per block: LDS histogram ->
// one global atomic per touched bucket -> packed (src<<7|dst&127) run writes.
// ---------------------------------------------------------------------------
__global__ void partition_kernel(const int* __restrict__ src,
                                 const int* __restrict__ dst,
                                 int* __restrict__ gcur,
                                 int* __restrict__ bkted, int E) {
    __shared__ int hist[NBKT];
    __shared__ int gbase[NBKT];
    int t = threadIdx.x;
    for (int b = t; b < NBKT; b += 256) hist[b] = 0;
    __syncthreads();

    int base = blockIdx.x * (256 * EPT);
    int rank[EPT];
#pragma unroll
    for (int i = 0; i < EPT; ++i) {
        int e = base + t + i * 256;
        rank[i] = -1;
        if (e < E) rank[i] = atomicAdd(&hist[dst[e] >> BSH], 1);
    }
    __syncthreads();
    for (int b = t; b < NBKT; b += 256) {
        int c = hist[b];
        gbase[b] = c ? atomicAdd(&gcur[b], c) : 0;
    }
    __syncthreads();
#pragma unroll
    for (int i = 0; i < EPT; ++i) {
        int e = base + t + i * 256;
        if (e < E) {
            int d = dst[e];
            int bk = d >> BSH;
            int pos = gbase[bk] + rank[i];
            if (pos < (bk + 1) * CAP)                        // overflow guard
                bkted[pos] = (src[e] << BSH) | (d & 127);
        }
    }
}

// ---------------------------------------------------------------------------
// Bucket-local CSR build: stage run in LDS, 128-bin hist + scan, LDS-cursor
// scatter, rewrite own region IN PLACE dst-sorted (all writes in a 10KB
// window -> write amp ~1). rowsc[g] = start(local)<<16 | cnt.
// ---------------------------------------------------------------------------
__global__ void bucketfill_kernel(const int* __restrict__ gcur,
                                  int* __restrict__ bkted,
                                  int* __restrict__ rowsc) {
    __shared__ int run[CAP];
    __shared__ int lhist[128];
    __shared__ int s[128];
    __shared__ int lcur[128];
    int b = blockIdx.x;
    int t = threadIdx.x;
    int cnt = gcur[b] - b * CAP;
    if (cnt > CAP) cnt = CAP;

    if (t < 128) lhist[t] = 0;
    __syncthreads();
    int* reg = bkted + b * CAP;
    for (int j = t; j < cnt; j += 256) {
        int p = reg[j];
        run[j] = p;
        atomicAdd(&lhist[p & 127], 1);
    }
    __syncthreads();
    if (t < 128) s[t] = lhist[t];
    __syncthreads();
    for (int off = 1; off < 128; off <<= 1) {         // Hillis-Steele inclusive
        int add = (t >= off && t < 128) ? s[t - off] : 0;
        __syncthreads();
        if (t < 128) s[t] += add;
        __syncthreads();
    }
    if (t < 128) lcur[t] = s[t] - lhist[t];           // exclusive
    __syncthreads();
    for (int j = t; j < cnt; j += 256) {
        int p = run[j];
        int pos = atomicAdd(&lcur[p & 127], 1);
        reg[pos] = p >> BSH;                          // src, dst-sorted in place
    }
    if (t < 128) {
        int g = (b << BSH) + t;
        if (g < NN) rowsc[g] = ((s[t] - lhist[t]) << 16) | lhist[t];
    }
}

// ---------------------------------------------------------------------------
// Pre-transform layer 1:  y1 = x @ W1_l ,  z1 = x @ W1_r + b1
// (mean-aggregation is linear: mean(x)@W = mean(x@W))
// ---------------------------------------------------------------------------
__global__ void transform1_kernel(const float* __restrict__ x,
                                  const float* __restrict__ Wl,
                                  const float* __restrict__ Wr,
                                  const float* __restrict__ b,
                                  float* __restrict__ y,
                                  float* __restrict__ z) {
    __shared__ float sWl[32 * 32];
    __shared__ float sWr[32 * 32];
    __shared__ float sb[32];
    int t = threadIdx.x;
    for (int i = t; i < 1024; i += 256) { sWl[i] = Wl[i]; sWr[i] = Wr[i]; }
    if (t < 32) sb[t] = b[t];
    __syncthreads();

    int node = blockIdx.x * 8 + (t >> 5);
    if (node >= NN) return;
    int o = t & 31;
    const float* xr = x + (size_t)node * 32;
    float accl = 0.0f, accr = sb[o];
#pragma unroll
    for (int k = 0; k < 32; ++k) {
        float xv = xr[k];
        accl += xv * sWl[k * 32 + o];
        accr += xv * sWr[k * 32 + o];
    }
    y[(size_t)node * 32 + o] = accl;
    z[(size_t)node * 32 + o] = accr;
}

// ---------------------------------------------------------------------------
// Pre-transform layer 2:  y2 = h @ W2_l ,  z2 = h @ W2_r + b2
// ---------------------------------------------------------------------------
__global__ void transform2_kernel(const float* __restrict__ h,
                                  const float* __restrict__ Wl,
                                  const float* __restrict__ Wr,
                                  const float* __restrict__ b,
                                  float* __restrict__ y,
                                  float* __restrict__ z) {
    __shared__ float sWl[32 * 16];
    __shared__ float sWr[32 * 16];
    __shared__ float sb[16];
    int t = threadIdx.x;
    for (int i = t; i < 512; i += 256) { sWl[i] = Wl[i]; sWr[i] = Wr[i]; }
    if (t < 16) sb[t] = b[t];
    __syncthreads();

    int node = blockIdx.x * 16 + (t >> 4);
    if (node >= NN) return;
    int o = t & 15;
    const float* hr = h + (size_t)node * 32;
    float accl = 0.0f, accr = sb[o];
#pragma unroll
    for (int k = 0; k < 32; ++k) {
        float hv = hr[k];
        accl += hv * sWl[k * 16 + o];
        accr += hv * sWr[k * 16 + o];
    }
    y[(size_t)node * 16 + o] = accl;
    z[(size_t)node * 16 + o] = accr;
}

// ---------------------------------------------------------------------------
// Node-parallel gather-mean + fused epilogue, layer 1 (8 lanes/node, float4):
//   h[d] = relu( mean_{s in row d} y1[s] + z1[d] )   -- h aliases z1 in place
// ---------------------------------------------------------------------------
__global__ void agg1_kernel(const float* __restrict__ y,
                            const int* __restrict__ rowsc,
                            const int* __restrict__ csr,
                            float* __restrict__ hz) {
    int tid = blockIdx.x * blockDim.x + threadIdx.x;
    int d = tid >> 3;
    int c = tid & 7;
    if (d >= NN) return;
    int sc = rowsc[d];
    int start = (d >> BSH) * CAP + (sc >> 16);
    int cnt = sc & 0xFFFF;
    float4 acc = {0.f, 0.f, 0.f, 0.f};
    for (int j = 0; j < cnt; ++j) {
        int s = csr[start + j];
        const float4 v = *reinterpret_cast<const float4*>(y + (size_t)s * 32 + c * 4);
        acc.x += v.x; acc.y += v.y; acc.z += v.z; acc.w += v.w;
    }
    float rd = 1.0f / fmaxf((float)cnt, 1.0f);
    float4* hp = reinterpret_cast<float4*>(hz + (size_t)d * 32 + c * 4);
    const float4 zv = *hp;
    float4 r;
    r.x = fmaxf(acc.x * rd + zv.x, 0.0f);
    r.y = fmaxf(acc.y * rd + zv.y, 0.0f);
    r.z = fmaxf(acc.z * rd + zv.z, 0.0f);
    r.w = fmaxf(acc.w * rd + zv.w, 0.0f);
    *hp = r;
}

// ---------------------------------------------------------------------------
// Layer 2 (4 lanes/node, 16-wide): out[d] = mean y2[s] + z2[d]
// ---------------------------------------------------------------------------
__global__ void agg2_kernel(const float* __restrict__ y,
                            const int* __restrict__ rowsc,
                            const int* __restrict__ csr,
                            const float* __restrict__ z,
                            float* __restrict__ out) {
    int tid = blockIdx.x * blockDim.x + threadIdx.x;
    int d = tid >> 2;
    int c = tid & 3;
    if (d >= NN) return;
    int sc = rowsc[d];
    int start = (d >> BSH) * CAP + (sc >> 16);
    int cnt = sc & 0xFFFF;
    float4 acc = {0.f, 0.f, 0.f, 0.f};
    for (int j = 0; j < cnt; ++j) {
        int s = csr[start + j];
        const float4 v = *reinterpret_cast<const float4*>(y + (size_t)s * 16 + c * 4);
        acc.x += v.x; acc.y += v.y; acc.z += v.z; acc.w += v.w;
    }
    float rd = 1.0f / fmaxf((float)cnt, 1.0f);
    const float4 zv = *reinterpret_cast<const float4*>(z + (size_t)d * 16 + c * 4);
    float4 r;
    r.x = acc.x * rd + zv.x;
    r.y = acc.y * rd + zv.y;
    r.z = acc.z * rd + zv.z;
    r.w = acc.w * rd + zv.w;
    *reinterpret_cast<float4*>(out + (size_t)d * 16 + c * 4) = r;
}

extern "C" void kernel_launch(void* const* d_in, const int* in_sizes, int n_in,
                              void* d_out, int out_size, void* d_ws, size_t ws_size,
                              hipStream_t stream) {
    const float* x   = (const float*)d_in[0];
    const int*   ei  = (const int*)d_in[1];
    const float* W1l = (const float*)d_in[2];
    const float* W1r = (const float*)d_in[3];
    const float* b1  = (const float*)d_in[4];
    const float* W2l = (const float*)d_in[5];
    const float* W2r = (const float*)d_in[6];
    const float* b2  = (const float*)d_in[7];
    float* out = (float*)d_out;

    const int E = in_sizes[1] / 2;
    const int* src = ei;
    const int* dst = ei + E;

    // Workspace: gcur[1024] | bkted/csr[NBKT*CAP] | rowsc[NN] | A | B  (~34 MB)
    //   A: y1, then reused as y2[NN*16] | z2[NN*16];  B: z1 -> h in place
    char* ws = (char*)d_ws;
    int*   gcur  = (int*)ws;                      ws += 1024 * 4;
    int*   bkted = (int*)ws;                      ws += (size_t)NBKT * CAP * 4;
    int*   rowsc = (int*)ws;                      ws += (size_t)NN * 4;
    float* A     = (float*)ws;                    ws += (size_t)NN * 32 * 4;
    float* B     = (float*)ws;

    float* y1  = A;
    float* z1h = B;
    float* y2  = A;
    float* z2  = A + (size_t)NN * 16;

    // CSR build: partition into bucket runs, then bucket-local sort (in place)
    initcur_kernel<<<(NBKT + 255) / 256, 256, 0, stream>>>(gcur);
    partition_kernel<<<(E + 256 * EPT - 1) / (256 * EPT), 256, 0, stream>>>(
        src, dst, gcur, bkted, E);
    bucketfill_kernel<<<NBKT, 256, 0, stream>>>(gcur, bkted, rowsc);

    // Layer 1
    transform1_kernel<<<(NN + 7) / 8, 256, 0, stream>>>(x, W1l, W1r, b1, y1, z1h);
    agg1_kernel<<<(NN * 8 + 255) / 256, 256, 0, stream>>>(y1, rowsc, bkted, z1h);

    // Layer 2
    transform2_kernel<<<(NN + 15) / 16, 256, 0, stream>>>(z1h, W2l, W2r, b2, y2, z2);
    agg2_kernel<<<(NN * 4 + 255) / 256, 256, 0, stream>>>(y2, rowsc, bkted, z2, out);
}

// Round 11
// 223.491 us; speedup vs baseline: 3.0688x; 1.0201x over previous
//
#include <hip/hip_runtime.h>

#define NN   100000
#define BSH  7                      // 128 nodes per bucket
#define NBKT ((NN + 127) / 128)     // 782
#define CAP  2560                   // slots per bucket (mean 2048, +11 sigma)
#define EPT  8                      // edges per thread in partition (R10: 32->8, 782 blocks)

// ---------------------------------------------------------------------------
// gcur[b] = b*CAP  (bucket cursor init; ws is poisoned before every launch)
// ---------------------------------------------------------------------------
__global__ void initcur_kernel(int* __restrict__ gcur) {
    int b = blockIdx.x * 256 + threadIdx.x;
    if (b < NBKT) gcur[b] = b * CAP;
}

// ---------------------------------------------------------------------------
// Partition edges by dst bucket. Per block: LDS histogram -> one global
// atomic per touched bucket -> packed (src<<7|dst&127) run writes.
// ---------------------------------------------------------------------------
__global__ void partition_kernel(const int* __restrict__ src,
                                 const int* __restrict__ dst,
                                 int* __restrict__ gcur,
                                 int* __restrict__ bkted, int E) {
    __shared__ int hist[NBKT];
    __shared__ int gbase[NBKT];
    int t = threadIdx.x;
    for (int b = t; b < NBKT; b += 256) hist[b] = 0;
    __syncthreads();

    int base = blockIdx.x * (256 * EPT);
    int rank[EPT];
#pragma unroll
    for (int i = 0; i < EPT; ++i) {
        int e = base + t + i * 256;
        rank[i] = -1;
        if (e < E) rank[i] = atomicAdd(&hist[dst[e] >> BSH], 1);
    }
    __syncthreads();
    for (int b = t; b < NBKT; b += 256) {
        int c = hist[b];
        gbase[b] = c ? atomicAdd(&gcur[b], c) : 0;
    }
    __syncthreads();
#pragma unroll
    for (int i = 0; i < EPT; ++i) {
        int e = base + t + i * 256;
        if (e < E) {
            int d = dst[e];
            int bk = d >> BSH;
            int pos = gbase[bk] + rank[i];
            if (pos < (bk + 1) * CAP)                        // overflow guard
                bkted[pos] = (src[e] << BSH) | (d & 127);
        }
    }
}

// ---------------------------------------------------------------------------
// Bucket-local CSR build: stage run in LDS, 128-bin hist + scan, LDS-cursor
// scatter, rewrite own region IN PLACE dst-sorted (write amp ~1).
// rowsc[g] = start(local)<<16 | cnt.
// ---------------------------------------------------------------------------
__global__ void bucketfill_kernel(const int* __restrict__ gcur,
                                  int* __restrict__ bkted,
                                  int* __restrict__ rowsc) {
    __shared__ int run[CAP];
    __shared__ int lhist[128];
    __shared__ int s[128];
    __shared__ int lcur[128];
    int b = blockIdx.x;
    int t = threadIdx.x;
    int cnt = gcur[b] - b * CAP;
    if (cnt > CAP) cnt = CAP;

    if (t < 128) lhist[t] = 0;
    __syncthreads();
    int* reg = bkted + b * CAP;
    for (int j = t; j < cnt; j += 256) {
        int p = reg[j];
        run[j] = p;
        atomicAdd(&lhist[p & 127], 1);
    }
    __syncthreads();
    if (t < 128) s[t] = lhist[t];
    __syncthreads();
    for (int off = 1; off < 128; off <<= 1) {         // Hillis-Steele inclusive
        int add = (t >= off && t < 128) ? s[t - off] : 0;
        __syncthreads();
        if (t < 128) s[t] += add;
        __syncthreads();
    }
    if (t < 128) lcur[t] = s[t] - lhist[t];           // exclusive
    __syncthreads();
    for (int j = t; j < cnt; j += 256) {
        int p = run[j];
        int pos = atomicAdd(&lcur[p & 127], 1);
        reg[pos] = p >> BSH;                          // src, dst-sorted in place
    }
    if (t < 128) {
        int g = (b << BSH) + t;
        if (g < NN) rowsc[g] = ((s[t] - lhist[t]) << 16) | lhist[t];
    }
}

// ---------------------------------------------------------------------------
// Pre-transform layer 1:  y1 = x @ W1_l ,  z1 = x @ W1_r + b1
// (mean-aggregation is linear: mean(x)@W = mean(x@W))
// ---------------------------------------------------------------------------
__global__ void transform1_kernel(const float* __restrict__ x,
                                  const float* __restrict__ Wl,
                                  const float* __restrict__ Wr,
                                  const float* __restrict__ b,
                                  float* __restrict__ y,
                                  float* __restrict__ z) {
    __shared__ float sWl[32 * 32];
    __shared__ float sWr[32 * 32];
    __shared__ float sb[32];
    int t = threadIdx.x;
    for (int i = t; i < 1024; i += 256) { sWl[i] = Wl[i]; sWr[i] = Wr[i]; }
    if (t < 32) sb[t] = b[t];
    __syncthreads();

    int node = blockIdx.x * 8 + (t >> 5);
    if (node >= NN) return;
    int o = t & 31;
    const float* xr = x + (size_t)node * 32;
    float accl = 0.0f, accr = sb[o];
#pragma unroll
    for (int k = 0; k < 32; ++k) {
        float xv = xr[k];
        accl += xv * sWl[k * 32 + o];
        accr += xv * sWr[k * 32 + o];
    }
    y[(size_t)node * 32 + o] = accl;
    z[(size_t)node * 32 + o] = accr;
}

// ---------------------------------------------------------------------------
// Pre-transform layer 2:  y2 = h @ W2_l ,  z2 = h @ W2_r + b2
// ---------------------------------------------------------------------------
__global__ void transform2_kernel(const float* __restrict__ h,
                                  const float* __restrict__ Wl,
                                  const float* __restrict__ Wr,
                                  const float* __restrict__ b,
                                  float* __restrict__ y,
                                  float* __restrict__ z) {
    __shared__ float sWl[32 * 16];
    __shared__ float sWr[32 * 16];
    __shared__ float sb[16];
    int t = threadIdx.x;
    for (int i = t; i < 512; i += 256) { sWl[i] = Wl[i]; sWr[i] = Wr[i]; }
    if (t < 16) sb[t] = b[t];
    __syncthreads();

    int node = blockIdx.x * 16 + (t >> 4);
    if (node >= NN) return;
    int o = t & 15;
    const float* hr = h + (size_t)node * 32;
    float accl = 0.0f, accr = sb[o];
#pragma unroll
    for (int k = 0; k < 32; ++k) {
        float hv = hr[k];
        accl += hv * sWl[k * 16 + o];
        accr += hv * sWr[k * 16 + o];
    }
    y[(size_t)node * 16 + o] = accl;
    z[(size_t)node * 16 + o] = accr;
}

// ---------------------------------------------------------------------------
// Node-parallel gather-mean + fused epilogue, layer 1 (8 lanes/node, float4).
// 2-way unrolled, dual accumulators -> 2 independent load chains (MLP).
//   h[d] = relu( mean_{s in row d} y1[s] + z1[d] )   -- h aliases z1 in place
// ---------------------------------------------------------------------------
__global__ void agg1_kernel(const float* __restrict__ y,
                            const int* __restrict__ rowsc,
                            const int* __restrict__ csr,
                            float* __restrict__ hz) {
    int tid = blockIdx.x * blockDim.x + threadIdx.x;
    int d = tid >> 3;
    int c = tid & 7;
    if (d >= NN) return;
    int sc = rowsc[d];
    int start = (d >> BSH) * CAP + (sc >> 16);
    int cnt = sc & 0xFFFF;
    float4 a0 = {0.f, 0.f, 0.f, 0.f};
    float4 a1 = {0.f, 0.f, 0.f, 0.f};
    int j = 0;
    for (; j + 1 < cnt; j += 2) {
        int s0 = csr[start + j];
        int s1 = csr[start + j + 1];
        const float4 v0 = *reinterpret_cast<const float4*>(y + (size_t)s0 * 32 + c * 4);
        const float4 v1 = *reinterpret_cast<const float4*>(y + (size_t)s1 * 32 + c * 4);
        a0.x += v0.x; a0.y += v0.y; a0.z += v0.z; a0.w += v0.w;
        a1.x += v1.x; a1.y += v1.y; a1.z += v1.z; a1.w += v1.w;
    }
    if (j < cnt) {
        int s0 = csr[start + j];
        const float4 v0 = *reinterpret_cast<const float4*>(y + (size_t)s0 * 32 + c * 4);
        a0.x += v0.x; a0.y += v0.y; a0.z += v0.z; a0.w += v0.w;
    }
    a0.x += a1.x; a0.y += a1.y; a0.z += a1.z; a0.w += a1.w;
    float rd = 1.0f / fmaxf((float)cnt, 1.0f);
    float4* hp = reinterpret_cast<float4*>(hz + (size_t)d * 32 + c * 4);
    const float4 zv = *hp;
    float4 r;
    r.x = fmaxf(a0.x * rd + zv.x, 0.0f);
    r.y = fmaxf(a0.y * rd + zv.y, 0.0f);
    r.z = fmaxf(a0.z * rd + zv.z, 0.0f);
    r.w = fmaxf(a0.w * rd + zv.w, 0.0f);
    *hp = r;
}

// ---------------------------------------------------------------------------
// Layer 2 (4 lanes/node, 16-wide), 2-way unrolled:
//   out[d] = mean y2[s] + z2[d]
// ---------------------------------------------------------------------------
__global__ void agg2_kernel(const float* __restrict__ y,
                            const int* __restrict__ rowsc,
                            const int* __restrict__ csr,
                            const float* __restrict__ z,
                            float* __restrict__ out) {
    int tid = blockIdx.x * blockDim.x + threadIdx.x;
    int d = tid >> 2;
    int c = tid & 3;
    if (d >= NN) return;
    int sc = rowsc[d];
    int start = (d >> BSH) * CAP + (sc >> 16);
    int cnt = sc & 0xFFFF;
    float4 a0 = {0.f, 0.f, 0.f, 0.f};
    float4 a1 = {0.f, 0.f, 0.f, 0.f};
    int j = 0;
    for (; j + 1 < cnt; j += 2) {
        int s0 = csr[start + j];
        int s1 = csr[start + j + 1];
        const float4 v0 = *reinterpret_cast<const float4*>(y + (size_t)s0 * 16 + c * 4);
        const float4 v1 = *reinterpret_cast<const float4*>(y + (size_t)s1 * 16 + c * 4);
        a0.x += v0.x; a0.y += v0.y; a0.z += v0.z; a0.w += v0.w;
        a1.x += v1.x; a1.y += v1.y; a1.z += v1.z; a1.w += v1.w;
    }
    if (j < cnt) {
        int s0 = csr[start + j];
        const float4 v0 = *reinterpret_cast<const float4*>(y + (size_t)s0 * 16 + c * 4);
        a0.x += v0.x; a0.y += v0.y; a0.z += v0.z; a0.w += v0.w;
    }
    a0.x += a1.x; a0.y += a1.y; a0.z += a1.z; a0.w += a1.w;
    float rd = 1.0f / fmaxf((float)cnt, 1.0f);
    const float4 zv = *reinterpret_cast<const float4*>(z + (size_t)d * 16 + c * 4);
    float4 r;
    r.x = a0.x * rd + zv.x;
    r.y = a0.y * rd + zv.y;
    r.z = a0.z * rd + zv.z;
    r.w = a0.w * rd + zv.w;
    *reinterpret_cast<float4*>(out + (size_t)d * 16 + c * 4) = r;
}

extern "C" void kernel_launch(void* const* d_in, const int* in_sizes, int n_in,
                              void* d_out, int out_size, void* d_ws, size_t ws_size,
                              hipStream_t stream) {
    const float* x   = (const float*)d_in[0];
    const int*   ei  = (const int*)d_in[1];
    const float* W1l = (const float*)d_in[2];
    const float* W1r = (const float*)d_in[3];
    const float* b1  = (const float*)d_in[4];
    const float* W2l = (const float*)d_in[5];
    const float* W2r = (const float*)d_in[6];
    const float* b2  = (const float*)d_in[7];
    float* out = (float*)d_out;

    const int E = in_sizes[1] / 2;
    const int* src = ei;
    const int* dst = ei + E;

    // Workspace: gcur[1024] | bkted/csr[NBKT*CAP] | rowsc[NN] | A | B  (~34 MB)
    //   A: y1, then reused as y2[NN*16] | z2[NN*16];  B: z1 -> h in place
    char* ws = (char*)d_ws;
    int*   gcur  = (int*)ws;                      ws += 1024 * 4;
    int*   bkted = (int*)ws;                      ws += (size_t)NBKT * CAP * 4;
    int*   rowsc = (int*)ws;                      ws += (size_t)NN * 4;
    float* A     = (float*)ws;                    ws += (size_t)NN * 32 * 4;
    float* B     = (float*)ws;

    float* y1  = A;
    float* z1h = B;
    float* y2  = A;
    float* z2  = A + (size_t)NN * 16;

    // CSR build: partition into bucket runs, then bucket-local sort (in place)
    initcur_kernel<<<(NBKT + 255) / 256, 256, 0, stream>>>(gcur);
    partition_kernel<<<(E + 256 * EPT - 1) / (256 * EPT), 256, 0, stream>>>(
        src, dst, gcur, bkted, E);
    bucketfill_kernel<<<NBKT, 256, 0, stream>>>(gcur, bkted, rowsc);

    // Layer 1
    transform1_kernel<<<(NN + 7) / 8, 256, 0, stream>>>(x, W1l, W1r, b1, y1, z1h);
    agg1_kernel<<<(NN * 8 + 255) / 256, 256, 0, stream>>>(y1, rowsc, bkted, z1h);

    // Layer 2
    transform2_kernel<<<(NN + 15) / 16, 256, 0, stream>>>(z1h, W2l, W2r, b2, y2, z2);
    agg2_kernel<<<(NN * 4 + 255) / 256, 256, 0, stream>>>(y2, rowsc, bkted, z2, out);
}

// Round 12
// 220.084 us; speedup vs baseline: 3.1163x; 1.0155x over previous
//
#include <hip/hip_runtime.h>

#define NN   100000
#define BSH  7                      // 128 nodes per bucket
#define NBKT ((NN + 127) / 128)     // 782
#define CAP  2560                   // slots per bucket (mean 2048, +11 sigma)
#define EPT  8                      // edges per thread in partition

// ---------------------------------------------------------------------------
// gcur[b] = b*CAP  (bucket cursor init; ws is poisoned before every launch)
// ---------------------------------------------------------------------------
__global__ void initcur_kernel(int* __restrict__ gcur) {
    int b = blockIdx.x * 256 + threadIdx.x;
    if (b < NBKT) gcur[b] = b * CAP;
}

// ---------------------------------------------------------------------------
// Partition edges by dst bucket. Per block: LDS histogram -> one global
// atomic per touched bucket -> packed (src<<7|dst&127) run writes.
// Measured floor ~47 us at both EPT=32 and EPT=8 (latency-bound rank chain).
// ---------------------------------------------------------------------------
__global__ void partition_kernel(const int* __restrict__ src,
                                 const int* __restrict__ dst,
                                 int* __restrict__ gcur,
                                 int* __restrict__ bkted, int E) {
    __shared__ int hist[NBKT];
    __shared__ int gbase[NBKT];
    int t = threadIdx.x;
    for (int b = t; b < NBKT; b += 256) hist[b] = 0;
    __syncthreads();

    int base = blockIdx.x * (256 * EPT);
    int rank[EPT];
#pragma unroll
    for (int i = 0; i < EPT; ++i) {
        int e = base + t + i * 256;
        rank[i] = -1;
        if (e < E) rank[i] = atomicAdd(&hist[dst[e] >> BSH], 1);
    }
    __syncthreads();
    for (int b = t; b < NBKT; b += 256) {
        int c = hist[b];
        gbase[b] = c ? atomicAdd(&gcur[b], c) : 0;
    }
    __syncthreads();
#pragma unroll
    for (int i = 0; i < EPT; ++i) {
        int e = base + t + i * 256;
        if (e < E) {
            int d = dst[e];
            int bk = d >> BSH;
            int pos = gbase[bk] + rank[i];
            if (pos < (bk + 1) * CAP)                        // overflow guard
                bkted[pos] = (src[e] << BSH) | (d & 127);
        }
    }
}

// ---------------------------------------------------------------------------
// Bucket-local CSR build: stage run in LDS, 128-bin hist + scan, LDS-cursor
// scatter, rewrite own region IN PLACE dst-sorted (write amp ~1).
// rowsc[g] = start(local)<<16 | cnt.
// ---------------------------------------------------------------------------
__global__ void bucketfill_kernel(const int* __restrict__ gcur,
                                  int* __restrict__ bkted,
                                  int* __restrict__ rowsc) {
    __shared__ int run[CAP];
    __shared__ int lhist[128];
    __shared__ int s[128];
    __shared__ int lcur[128];
    int b = blockIdx.x;
    int t = threadIdx.x;
    int cnt = gcur[b] - b * CAP;
    if (cnt > CAP) cnt = CAP;

    if (t < 128) lhist[t] = 0;
    __syncthreads();
    int* reg = bkted + b * CAP;
    for (int j = t; j < cnt; j += 256) {
        int p = reg[j];
        run[j] = p;
        atomicAdd(&lhist[p & 127], 1);
    }
    __syncthreads();
    if (t < 128) s[t] = lhist[t];
    __syncthreads();
    for (int off = 1; off < 128; off <<= 1) {         // Hillis-Steele inclusive
        int add = (t >= off && t < 128) ? s[t - off] : 0;
        __syncthreads();
        if (t < 128) s[t] += add;
        __syncthreads();
    }
    if (t < 128) lcur[t] = s[t] - lhist[t];           // exclusive
    __syncthreads();
    for (int j = t; j < cnt; j += 256) {
        int p = run[j];
        int pos = atomicAdd(&lcur[p & 127], 1);
        reg[pos] = p >> BSH;                          // src, dst-sorted in place
    }
    if (t < 128) {
        int g = (b << BSH) + t;
        if (g < NN) rowsc[g] = ((s[t] - lhist[t]) << 16) | lhist[t];
    }
}

// ---------------------------------------------------------------------------
// Pre-transform layer 1:  y1 = x @ W1_l ,  z1 = x @ W1_r + b1
// (mean-aggregation is linear: mean(x)@W = mean(x@W))
// ---------------------------------------------------------------------------
__global__ void transform1_kernel(const float* __restrict__ x,
                                  const float* __restrict__ Wl,
                                  const float* __restrict__ Wr,
                                  const float* __restrict__ b,
                                  float* __restrict__ y,
                                  float* __restrict__ z) {
    __shared__ float sWl[32 * 32];
    __shared__ float sWr[32 * 32];
    __shared__ float sb[32];
    int t = threadIdx.x;
    for (int i = t; i < 1024; i += 256) { sWl[i] = Wl[i]; sWr[i] = Wr[i]; }
    if (t < 32) sb[t] = b[t];
    __syncthreads();

    int node = blockIdx.x * 8 + (t >> 5);
    if (node >= NN) return;
    int o = t & 31;
    const float* xr = x + (size_t)node * 32;
    float accl = 0.0f, accr = sb[o];
#pragma unroll
    for (int k = 0; k < 32; ++k) {
        float xv = xr[k];
        accl += xv * sWl[k * 32 + o];
        accr += xv * sWr[k * 32 + o];
    }
    y[(size_t)node * 32 + o] = accl;
    z[(size_t)node * 32 + o] = accr;
}

// ---------------------------------------------------------------------------
// Pre-transform layer 2:  y2 = h @ W2_l ,  z2 = h @ W2_r + b2
// ---------------------------------------------------------------------------
__global__ void transform2_kernel(const float* __restrict__ h,
                                  const float* __restrict__ Wl,
                                  const float* __restrict__ Wr,
                                  const float* __restrict__ b,
                                  float* __restrict__ y,
                                  float* __restrict__ z) {
    __shared__ float sWl[32 * 16];
    __shared__ float sWr[32 * 16];
    __shared__ float sb[16];
    int t = threadIdx.x;
    for (int i = t; i < 512; i += 256) { sWl[i] = Wl[i]; sWr[i] = Wr[i]; }
    if (t < 16) sb[t] = b[t];
    __syncthreads();

    int node = blockIdx.x * 16 + (t >> 4);
    if (node >= NN) return;
    int o = t & 15;
    const float* hr = h + (size_t)node * 32;
    float accl = 0.0f, accr = sb[o];
#pragma unroll
    for (int k = 0; k < 32; ++k) {
        float hv = hr[k];
        accl += hv * sWl[k * 16 + o];
        accr += hv * sWr[k * 16 + o];
    }
    y[(size_t)node * 16 + o] = accl;
    z[(size_t)node * 16 + o] = accr;
}

// ---------------------------------------------------------------------------
// Gather-mean layer 1, shuffle-batched: 8 lanes/node. Per 8-edge chunk,
// lane c loads csr[start+j+c] (coalesced), 8x shfl broadcasts -> 8
// independent row-loads in flight (MLP=8 vs 2).
//   h[d] = relu( mean_{s in row d} y1[s] + z1[d] )   -- h aliases z1 in place
// ---------------------------------------------------------------------------
__global__ void agg1_kernel(const float* __restrict__ y,
                            const int* __restrict__ rowsc,
                            const int* __restrict__ csr,
                            float* __restrict__ hz) {
    int tid = blockIdx.x * blockDim.x + threadIdx.x;
    int d = tid >> 3;
    int c = tid & 7;
    if (d >= NN) return;
    int sc = rowsc[d];
    int start = (d >> BSH) * CAP + (sc >> 16);
    int cnt = sc & 0xFFFF;
    float4 acc = {0.f, 0.f, 0.f, 0.f};
    int j = 0;
    for (; j + 8 <= cnt; j += 8) {
        int idx = csr[start + j + c];                 // coalesced across group
#pragma unroll
        for (int k = 0; k < 8; ++k) {
            int s = __shfl(idx, k, 8);
            const float4 v = *reinterpret_cast<const float4*>(y + (size_t)s * 32 + c * 4);
            acc.x += v.x; acc.y += v.y; acc.z += v.z; acc.w += v.w;
        }
    }
    for (; j < cnt; ++j) {
        int s = csr[start + j];
        const float4 v = *reinterpret_cast<const float4*>(y + (size_t)s * 32 + c * 4);
        acc.x += v.x; acc.y += v.y; acc.z += v.z; acc.w += v.w;
    }
    float rd = 1.0f / fmaxf((float)cnt, 1.0f);
    float4* hp = reinterpret_cast<float4*>(hz + (size_t)d * 32 + c * 4);
    const float4 zv = *hp;
    float4 r;
    r.x = fmaxf(acc.x * rd + zv.x, 0.0f);
    r.y = fmaxf(acc.y * rd + zv.y, 0.0f);
    r.z = fmaxf(acc.z * rd + zv.z, 0.0f);
    r.w = fmaxf(acc.w * rd + zv.w, 0.0f);
    *hp = r;
}

// ---------------------------------------------------------------------------
// Gather-mean layer 2, shuffle-batched: 4 lanes/node, 4-edge chunks.
//   out[d] = mean y2[s] + z2[d]
// ---------------------------------------------------------------------------
__global__ void agg2_kernel(const float* __restrict__ y,
                            const int* __restrict__ rowsc,
                            const int* __restrict__ csr,
                            const float* __restrict__ z,
                            float* __restrict__ out) {
    int tid = blockIdx.x * blockDim.x + threadIdx.x;
    int d = tid >> 2;
    int c = tid & 3;
    if (d >= NN) return;
    int sc = rowsc[d];
    int start = (d >> BSH) * CAP + (sc >> 16);
    int cnt = sc & 0xFFFF;
    float4 acc = {0.f, 0.f, 0.f, 0.f};
    int j = 0;
    for (; j + 4 <= cnt; j += 4) {
        int idx = csr[start + j + c];                 // coalesced across group
#pragma unroll
        for (int k = 0; k < 4; ++k) {
            int s = __shfl(idx, k, 4);
            const float4 v = *reinterpret_cast<const float4*>(y + (size_t)s * 16 + c * 4);
            acc.x += v.x; acc.y += v.y; acc.z += v.z; acc.w += v.w;
        }
    }
    for (; j < cnt; ++j) {
        int s = csr[start + j];
        const float4 v = *reinterpret_cast<const float4*>(y + (size_t)s * 16 + c * 4);
        acc.x += v.x; acc.y += v.y; acc.z += v.z; acc.w += v.w;
    }
    float rd = 1.0f / fmaxf((float)cnt, 1.0f);
    const float4 zv = *reinterpret_cast<const float4*>(z + (size_t)d * 16 + c * 4);
    float4 r;
    r.x = acc.x * rd + zv.x;
    r.y = acc.y * rd + zv.y;
    r.z = acc.z * rd + zv.z;
    r.w = acc.w * rd + zv.w;
    *reinterpret_cast<float4*>(out + (size_t)d * 16 + c * 4) = r;
}

extern "C" void kernel_launch(void* const* d_in, const int* in_sizes, int n_in,
                              void* d_out, int out_size, void* d_ws, size_t ws_size,
                              hipStream_t stream) {
    const float* x   = (const float*)d_in[0];
    const int*   ei  = (const int*)d_in[1];
    const float* W1l = (const float*)d_in[2];
    const float* W1r = (const float*)d_in[3];
    const float* b1  = (const float*)d_in[4];
    const float* W2l = (const float*)d_in[5];
    const float* W2r = (const float*)d_in[6];
    const float* b2  = (const float*)d_in[7];
    float* out = (float*)d_out;

    const int E = in_sizes[1] / 2;
    const int* src = ei;
    const int* dst = ei + E;

    // Workspace: gcur[1024] | bkted/csr[NBKT*CAP] | rowsc[NN] | A | B  (~34 MB)
    //   A: y1, then reused as y2[NN*16] | z2[NN*16];  B: z1 -> h in place
    char* ws = (char*)d_ws;
    int*   gcur  = (int*)ws;                      ws += 1024 * 4;
    int*   bkted = (int*)ws;                      ws += (size_t)NBKT * CAP * 4;
    int*   rowsc = (int*)ws;                      ws += (size_t)NN * 4;
    float* A     = (float*)ws;                    ws += (size_t)NN * 32 * 4;
    float* B     = (float*)ws;

    float* y1  = A;
    float* z1h = B;
    float* y2  = A;
    float* z2  = A + (size_t)NN * 16;

    // CSR build: partition into bucket runs, then bucket-local sort (in place)
    initcur_kernel<<<(NBKT + 255) / 256, 256, 0, stream>>>(gcur);
    partition_kernel<<<(E + 256 * EPT - 1) / (256 * EPT), 256, 0, stream>>>(
        src, dst, gcur, bkted, E);
    bucketfill_kernel<<<NBKT, 256, 0, stream>>>(gcur, bkted, rowsc);

    // Layer 1
    transform1_kernel<<<(NN + 7) / 8, 256, 0, stream>>>(x, W1l, W1r, b1, y1, z1h);
    agg1_kernel<<<(NN * 8 + 255) / 256, 256, 0, stream>>>(y1, rowsc, bkted, z1h);

    // Layer 2
    transform2_kernel<<<(NN + 15) / 16, 256, 0, stream>>>(z1h, W2l, W2r, b2, y2, z2);
    agg2_kernel<<<(NN * 4 + 255) / 256, 256, 0, stream>>>(y2, rowsc, bkted, z2, out);
}

// Round 15
// 212.578 us; speedup vs baseline: 3.2263x; 1.0353x over previous
//
#include <hip/hip_runtime.h>

#define NN   100000
#define BSH  7                      // 128 nodes per bucket
#define NBKT ((NN + 127) / 128)     // 782
#define CAP  2560                   // slots per bucket (mean 2048, +11 sigma)
#define EPT  8                      // edges per thread in partition

typedef unsigned int uint;
typedef unsigned short ushort;

// fp32 -> bf16 (round-to-nearest-even), returned as raw 16-bit pattern
__device__ inline ushort f2bf(float f) {
    uint u = __float_as_uint(f);
    uint r = (u + 0x7FFFu + ((u >> 16) & 1u)) >> 16;
    return (ushort)r;
}

// ---------------------------------------------------------------------------
// gcur[b] = b*CAP  (bucket cursor init; ws is poisoned before every launch)
// ---------------------------------------------------------------------------
__global__ void initcur_kernel(int* __restrict__ gcur) {
    int b = blockIdx.x * 256 + threadIdx.x;
    if (b < NBKT) gcur[b] = b * CAP;
}

// ---------------------------------------------------------------------------
// Partition edges by dst bucket. Measured floor ~47 us (EPT=8 and 32 equal).
// ---------------------------------------------------------------------------
__global__ void partition_kernel(const int* __restrict__ src,
                                 const int* __restrict__ dst,
                                 int* __restrict__ gcur,
                                 int* __restrict__ bkted, int E) {
    __shared__ int hist[NBKT];
    __shared__ int gbase[NBKT];
    int t = threadIdx.x;
    for (int b = t; b < NBKT; b += 256) hist[b] = 0;
    __syncthreads();

    int base = blockIdx.x * (256 * EPT);
    int rank[EPT];
#pragma unroll
    for (int i = 0; i < EPT; ++i) {
        int e = base + t + i * 256;
        rank[i] = -1;
        if (e < E) rank[i] = atomicAdd(&hist[dst[e] >> BSH], 1);
    }
    __syncthreads();
    for (int b = t; b < NBKT; b += 256) {
        int c = hist[b];
        gbase[b] = c ? atomicAdd(&gcur[b], c) : 0;
    }
    __syncthreads();
#pragma unroll
    for (int i = 0; i < EPT; ++i) {
        int e = base + t + i * 256;
        if (e < E) {
            int d = dst[e];
            int bk = d >> BSH;
            int pos = gbase[bk] + rank[i];
            if (pos < (bk + 1) * CAP)                        // overflow guard
                bkted[pos] = (src[e] << BSH) | (d & 127);
        }
    }
}

// ---------------------------------------------------------------------------
// Bucket-local CSR build (512 threads: 4 serial iters/thread instead of 8).
// rowsc[g] = start(local)<<16 | cnt.
// ---------------------------------------------------------------------------
__global__ void bucketfill_kernel(const int* __restrict__ gcur,
                                  int* __restrict__ bkted,
                                  int* __restrict__ rowsc) {
    __shared__ int run[CAP];
    __shared__ int lhist[128];
    __shared__ int s[128];
    __shared__ int lcur[128];
    int b = blockIdx.x;
    int t = threadIdx.x;
    int cnt = gcur[b] - b * CAP;
    if (cnt > CAP) cnt = CAP;

    if (t < 128) lhist[t] = 0;
    __syncthreads();
    int* reg = bkted + b * CAP;
    for (int j = t; j < cnt; j += 512) {
        int p = reg[j];
        run[j] = p;
        atomicAdd(&lhist[p & 127], 1);
    }
    __syncthreads();
    if (t < 128) s[t] = lhist[t];
    __syncthreads();
    for (int off = 1; off < 128; off <<= 1) {         // Hillis-Steele inclusive
        int add = (t >= off && t < 128) ? s[t - off] : 0;
        __syncthreads();
        if (t < 128) s[t] += add;
        __syncthreads();
    }
    if (t < 128) lcur[t] = s[t] - lhist[t];           // exclusive
    __syncthreads();
    for (int j = t; j < cnt; j += 512) {
        int p = run[j];
        int pos = atomicAdd(&lcur[p & 127], 1);
        reg[pos] = p >> BSH;                          // src, dst-sorted in place
    }
    if (t < 128) {
        int g = (b << BSH) + t;
        if (g < NN) rowsc[g] = ((s[t] - lhist[t]) << 16) | lhist[t];
    }
}

// ---------------------------------------------------------------------------
// Pre-transform layer 1:  y1 = bf16(x @ W1_l),  z1 = x @ W1_r + b1 (fp32)
// ---------------------------------------------------------------------------
__global__ void transform1_kernel(const float* __restrict__ x,
                                  const float* __restrict__ Wl,
                                  const float* __restrict__ Wr,
                                  const float* __restrict__ b,
                                  ushort* __restrict__ yb,
                                  float* __restrict__ z) {
    __shared__ float sWl[32 * 32];
    __shared__ float sWr[32 * 32];
    __shared__ float sb[32];
    int t = threadIdx.x;
    for (int i = t; i < 1024; i += 256) { sWl[i] = Wl[i]; sWr[i] = Wr[i]; }
    if (t < 32) sb[t] = b[t];
    __syncthreads();

    int node = blockIdx.x * 8 + (t >> 5);
    if (node >= NN) return;
    int o = t & 31;
    const float* xr = x + (size_t)node * 32;
    float accl = 0.0f, accr = sb[o];
#pragma unroll
    for (int k = 0; k < 32; ++k) {
        float xv = xr[k];
        accl += xv * sWl[k * 32 + o];
        accr += xv * sWr[k * 32 + o];
    }
    yb[(size_t)node * 32 + o] = f2bf(accl);
    z[(size_t)node * 32 + o] = accr;
}

// ---------------------------------------------------------------------------
// Pre-transform layer 2:  y2 = h @ W2_l ,  z2 = h @ W2_r + b2   (fp32)
// ---------------------------------------------------------------------------
__global__ void transform2_kernel(const float* __restrict__ h,
                                  const float* __restrict__ Wl,
                                  const float* __restrict__ Wr,
                                  const float* __restrict__ b,
                                  float* __restrict__ y,
                                  float* __restrict__ z) {
    __shared__ float sWl[32 * 16];
    __shared__ float sWr[32 * 16];
    __shared__ float sb[16];
    int t = threadIdx.x;
    for (int i = t; i < 512; i += 256) { sWl[i] = Wl[i]; sWr[i] = Wr[i]; }
    if (t < 16) sb[t] = b[t];
    __syncthreads();

    int node = blockIdx.x * 16 + (t >> 4);
    if (node >= NN) return;
    int o = t & 15;
    const float* hr = h + (size_t)node * 32;
    float accl = 0.0f, accr = sb[o];
#pragma unroll
    for (int k = 0; k < 32; ++k) {
        float hv = hr[k];
        accl += hv * sWl[k * 16 + o];
        accr += hv * sWr[k * 16 + o];
    }
    y[(size_t)node * 16 + o] = accl;
    z[(size_t)node * 16 + o] = accr;
}

// ---------------------------------------------------------------------------
// Gather-mean layer 1, bf16 rows: 4 lanes/node, 16B uint4 = 8 bf16 per lane.
// Shuffle-batched csr loads (4-edge chunks). Gather bytes halved vs fp32.
//   h[d] = relu( mean_{s in row d} y1[s] + z1[d] )   -- h aliases z1 in place
// ---------------------------------------------------------------------------
__global__ void agg1_kernel(const ushort* __restrict__ yb,
                            const int* __restrict__ rowsc,
                            const int* __restrict__ csr,
                            float* __restrict__ hz) {
    int tid = blockIdx.x * blockDim.x + threadIdx.x;
    int d = tid >> 2;
    int c = tid & 3;                     // 4 lanes/node, elems 8c..8c+7
    if (d >= NN) return;
    int sc = rowsc[d];
    int start = (d >> BSH) * CAP + (sc >> 16);
    int cnt = sc & 0xFFFF;
    float a[8] = {0.f, 0.f, 0.f, 0.f, 0.f, 0.f, 0.f, 0.f};
    int j = 0;
    for (; j + 4 <= cnt; j += 4) {
        int idx = csr[start + j + c];    // coalesced across 4-lane group
#pragma unroll
        for (int k = 0; k < 4; ++k) {
            int s = __shfl(idx, k, 4);
            const uint4 v = *reinterpret_cast<const uint4*>(yb + (size_t)s * 32 + c * 8);
            a[0] += __uint_as_float(v.x << 16);
            a[1] += __uint_as_float(v.x & 0xFFFF0000u);
            a[2] += __uint_as_float(v.y << 16);
            a[3] += __uint_as_float(v.y & 0xFFFF0000u);
            a[4] += __uint_as_float(v.z << 16);
            a[5] += __uint_as_float(v.z & 0xFFFF0000u);
            a[6] += __uint_as_float(v.w << 16);
            a[7] += __uint_as_float(v.w & 0xFFFF0000u);
        }
    }
    for (; j < cnt; ++j) {
        int s = csr[start + j];
        const uint4 v = *reinterpret_cast<const uint4*>(yb + (size_t)s * 32 + c * 8);
        a[0] += __uint_as_float(v.x << 16);
        a[1] += __uint_as_float(v.x & 0xFFFF0000u);
        a[2] += __uint_as_float(v.y << 16);
        a[3] += __uint_as_float(v.y & 0xFFFF0000u);
        a[4] += __uint_as_float(v.z << 16);
        a[5] += __uint_as_float(v.z & 0xFFFF0000u);
        a[6] += __uint_as_float(v.w << 16);
        a[7] += __uint_as_float(v.w & 0xFFFF0000u);
    }
    float rd = 1.0f / fmaxf((float)cnt, 1.0f);
    float* hp = hz + (size_t)d * 32 + c * 8;
    float4 z0 = *reinterpret_cast<float4*>(hp);
    float4 z1 = *reinterpret_cast<float4*>(hp + 4);
    float4 r0, r1;
    r0.x = fmaxf(a[0] * rd + z0.x, 0.0f);
    r0.y = fmaxf(a[1] * rd + z0.y, 0.0f);
    r0.z = fmaxf(a[2] * rd + z0.z, 0.0f);
    r0.w = fmaxf(a[3] * rd + z0.w, 0.0f);
    r1.x = fmaxf(a[4] * rd + z1.x, 0.0f);
    r1.y = fmaxf(a[5] * rd + z1.y, 0.0f);
    r1.z = fmaxf(a[6] * rd + z1.z, 0.0f);
    r1.w = fmaxf(a[7] * rd + z1.w, 0.0f);
    *reinterpret_cast<float4*>(hp) = r0;
    *reinterpret_cast<float4*>(hp + 4) = r1;
}

// ---------------------------------------------------------------------------
// Gather-mean layer 2 (fp32, 16-wide): 4 lanes/node, 4-edge shuffle chunks.
//   out[d] = mean y2[s] + z2[d]
// ---------------------------------------------------------------------------
__global__ void agg2_kernel(const float* __restrict__ y,
                            const int* __restrict__ rowsc,
                            const int* __restrict__ csr,
                            const float* __restrict__ z,
                            float* __restrict__ out) {
    int tid = blockIdx.x * blockDim.x + threadIdx.x;
    int d = tid >> 2;
    int c = tid & 3;
    if (d >= NN) return;
    int sc = rowsc[d];
    int start = (d >> BSH) * CAP + (sc >> 16);
    int cnt = sc & 0xFFFF;
    float4 acc = {0.f, 0.f, 0.f, 0.f};
    int j = 0;
    for (; j + 4 <= cnt; j += 4) {
        int idx = csr[start + j + c];
#pragma unroll
        for (int k = 0; k < 4; ++k) {
            int s = __shfl(idx, k, 4);
            const float4 v = *reinterpret_cast<const float4*>(y + (size_t)s * 16 + c * 4);
            acc.x += v.x; acc.y += v.y; acc.z += v.z; acc.w += v.w;
        }
    }
    for (; j < cnt; ++j) {
        int s = csr[start + j];
        const float4 v = *reinterpret_cast<const float4*>(y + (size_t)s * 16 + c * 4);
        acc.x += v.x; acc.y += v.y; acc.z += v.z; acc.w += v.w;
    }
    float rd = 1.0f / fmaxf((float)cnt, 1.0f);
    const float4 zv = *reinterpret_cast<const float4*>(z + (size_t)d * 16 + c * 4);
    float4 r;
    r.x = acc.x * rd + zv.x;
    r.y = acc.y * rd + zv.y;
    r.z = acc.z * rd + zv.z;
    r.w = acc.w * rd + zv.w;
    *reinterpret_cast<float4*>(out + (size_t)d * 16 + c * 4) = r;
}

extern "C" void kernel_launch(void* const* d_in, const int* in_sizes, int n_in,
                              void* d_out, int out_size, void* d_ws, size_t ws_size,
                              hipStream_t stream) {
    const float* x   = (const float*)d_in[0];
    const int*   ei  = (const int*)d_in[1];
    const float* W1l = (const float*)d_in[2];
    const float* W1r = (const float*)d_in[3];
    const float* b1  = (const float*)d_in[4];
    const float* W2l = (const float*)d_in[5];
    const float* W2r = (const float*)d_in[6];
    const float* b2  = (const float*)d_in[7];
    float* out = (float*)d_out;

    const int E = in_sizes[1] / 2;
    const int* src = ei;
    const int* dst = ei + E;

    // Workspace: gcur[1024] | bkted/csr[NBKT*CAP] | rowsc[NN] | A | B  (~34 MB)
    //   A: y1(bf16, first 6.4MB), later y2[NN*16]f32 | z2[NN*16]f32
    //   B: z1 (fp32), overwritten in place by h
    //   (y1b dead before transform2 writes y2/z2 into A — no overlap hazard)
    char* ws = (char*)d_ws;
    int*   gcur  = (int*)ws;                      ws += 1024 * 4;
    int*   bkted = (int*)ws;                      ws += (size_t)NBKT * CAP * 4;
    int*   rowsc = (int*)ws;                      ws += (size_t)NN * 4;
    float* A     = (float*)ws;                    ws += (size_t)NN * 32 * 4;
    float* B     = (float*)ws;

    ushort* y1b = (ushort*)A;
    float*  z1h = B;
    float*  y2  = A;
    float*  z2  = A + (size_t)NN * 16;

    // CSR build: partition into bucket runs, then bucket-local sort (in place)
    initcur_kernel<<<(NBKT + 255) / 256, 256, 0, stream>>>(gcur);
    partition_kernel<<<(E + 256 * EPT - 1) / (256 * EPT), 256, 0, stream>>>(
        src, dst, gcur, bkted, E);
    bucketfill_kernel<<<NBKT, 512, 0, stream>>>(gcur, bkted, rowsc);

    // Layer 1
    transform1_kernel<<<(NN + 7) / 8, 256, 0, stream>>>(x, W1l, W1r, b1, y1b, z1h);
    agg1_kernel<<<(NN * 4 + 255) / 256, 256, 0, stream>>>(y1b, rowsc, bkted, z1h);

    // Layer 2
    transform2_kernel<<<(NN + 15) / 16, 256, 0, stream>>>(z1h, W2l, W2r, b2, y2, z2);
    agg2_kernel<<<(NN * 4 + 255) / 256, 256, 0, stream>>>(y2, rowsc, bkted, z2, out);
}